// Round 5
// baseline (66.478 us; speedup 1.0000x reference)
//
#include <hip/hip_runtime.h>

// out[pos,e] = W[e, tokens[pos]]  (one_hot @ W.T == embedding gather).
// R5: DENSE-STREAM compact. R4's sparse-sector read ran at ~2.2 TB/s (gap-ridden
// DRAM stream, 28% lane utilization). Reading ALL of W coalesced at streaming
// rate (~7 TB/s, demonstrated by the harness fills) is faster: 206MB/7 < 96MB/2.2.
//  setup  (1 block): LDS mask -> scan -> rank; duplicate chains rep/nxt.
//  compact(12608 blk): thread owns one v column x 16 e; dense unconditional
//  loads (256B/wave-instr), present columns chain-walk write 64B chunks.

#define VOCAB 50257
#define EMBED 1024
#define NTOK  4096
#define NWPAD 2048            // padded mask words (>= ceil(50257/32)=1571)
#define VTILE 256             // vocab span per compact block (1 v per thread)
#define NVSTRIPS 197          // ceil(50257/256)
#define ETILE 16              // e-rows per compact block; 16*4B = 64B chunk
#define NETILES (EMBED / ETILE)   // 64

__global__ __launch_bounds__(1024) void setup_kernel(
    const int* __restrict__ tokens,
    unsigned int* __restrict__ g_mask,   // [NWPAD]
    int* __restrict__ g_wb,              // [NWPAD]
    int* __restrict__ g_rep,             // [NTOK] head pos per rank
    int* __restrict__ g_nxt) {           // [NTOK] chain
    __shared__ unsigned int mask[NWPAD];
    __shared__ int wb[NWPAD];
    __shared__ int rep[NTOK];
    __shared__ int nxt[NTOK];
    __shared__ int wsum[16];
    const int t = threadIdx.x;

    mask[t] = 0u; mask[t + 1024] = 0u;
    rep[t] = -1; rep[t + 1024] = -1; rep[t + 2048] = -1; rep[t + 3072] = -1;
    __syncthreads();

    const int4 tk = reinterpret_cast<const int4*>(tokens)[t];  // 4 tokens/thread
    atomicOr(&mask[tk.x >> 5], 1u << (tk.x & 31));
    atomicOr(&mask[tk.y >> 5], 1u << (tk.y & 31));
    atomicOr(&mask[tk.z >> 5], 1u << (tk.z & 31));
    atomicOr(&mask[tk.w >> 5], 1u << (tk.w & 31));
    __syncthreads();

    // exclusive scan of per-word popcounts (2 words/thread)
    const unsigned int w0 = mask[2 * t], w1 = mask[2 * t + 1];
    const int c0 = __popc(w0), c1 = __popc(w1);
    const int sum = c0 + c1;
    const int lane = t & 63, wid = t >> 6;
    int inc = sum;
#pragma unroll
    for (int d = 1; d < 64; d <<= 1) {
        const int u = __shfl_up(inc, d, 64);
        if (lane >= d) inc += u;
    }
    if (lane == 63) wsum[wid] = inc;
    __syncthreads();
    if (t == 0) {
        int acc = 0;
#pragma unroll
        for (int i = 0; i < 16; ++i) { const int v = wsum[i]; wsum[i] = acc; acc += v; }
    }
    __syncthreads();
    const int excl = wsum[wid] + inc - sum;
    wb[2 * t] = excl;
    wb[2 * t + 1] = excl + c0;
    __syncthreads();

    // duplicate chains (order race-dependent; output content order-independent)
#pragma unroll
    for (int j = 0; j < 4; ++j) {
        const int pos = t * 4 + j;
        const int tok = (j == 0) ? tk.x : (j == 1) ? tk.y : (j == 2) ? tk.z : tk.w;
        const unsigned int m = mask[tok >> 5];
        const int r = wb[tok >> 5] + __popc(m & ((1u << (tok & 31)) - 1u));
        nxt[pos] = atomicExch(&rep[r], pos);
    }
    __syncthreads();

    g_mask[t] = mask[t]; g_mask[t + 1024] = mask[t + 1024];
    g_wb[t] = wb[t];     g_wb[t + 1024] = wb[t + 1024];
    g_rep[t] = rep[t]; g_rep[t + 1024] = rep[t + 1024];
    g_rep[t + 2048] = rep[t + 2048]; g_rep[t + 3072] = rep[t + 3072];
    g_nxt[t] = nxt[t]; g_nxt[t + 1024] = nxt[t + 1024];
    g_nxt[t + 2048] = nxt[t + 2048]; g_nxt[t + 3072] = nxt[t + 3072];
}

__global__ __launch_bounds__(256) void compact_dense_kernel(
    const float* __restrict__ W,
    const unsigned int* __restrict__ mask,
    const int* __restrict__ wb,
    const int* __restrict__ rep,
    const int* __restrict__ nxt,
    float* __restrict__ out) {
    const int strip = (int)blockIdx.x / NETILES;
    const int etile = (int)blockIdx.x % NETILES;
    const int v = strip * VTILE + (int)threadIdx.x;  // one column per thread
    const int e0 = etile * ETILE;
    if (v >= VOCAB) return;                          // tail strip only

    const unsigned int m = mask[v >> 5];
    const bool present = (m >> (v & 31)) & 1u;

    // DENSE unconditional loads: consecutive lanes -> consecutive addresses,
    // 256B contiguous per wave-instruction. Nontemporal: W streams once; keep
    // L2 for mask/wb/rep/nxt and the out write-combining.
    float val[ETILE];
    const float* __restrict__ src = W + (size_t)e0 * VOCAB + v;
#pragma unroll
    for (int q = 0; q < ETILE; ++q)
        val[q] = __builtin_nontemporal_load(&src[(size_t)q * VOCAB]);
    // Keep the loads OUT of the divergent branch (else the compiler sinks them
    // and re-creates the sparse gap-ridden stream).
#pragma unroll
    for (int q = 0; q < ETILE; ++q) asm volatile("" : "+v"(val[q]));

    if (!present) return;
    const int r = wb[v >> 5] + __popc(m & ((1u << (v & 31)) - 1u));

    float4 f[4];
#pragma unroll
    for (int q = 0; q < 4; ++q)
        f[q] = make_float4(val[4 * q], val[4 * q + 1], val[4 * q + 2], val[4 * q + 3]);

    int p = rep[r];
    do {
        float4* __restrict__ dst = reinterpret_cast<float4*>(out + (size_t)p * EMBED + e0);
#pragma unroll
        for (int q = 0; q < 4; ++q) dst[q] = f[q];   // 64B contiguous chunk
        p = nxt[p];
    } while (p >= 0);
}

// Fallback (R1 kernel) if the workspace is too small.
__global__ __launch_bounds__(256) void embed_gather_kernel(
    const int* __restrict__ tokens,
    const float* __restrict__ W,
    float* __restrict__ out) {
    const int pos = blockIdx.x;
    const int tok = tokens[pos];
    const int e0 = (int)threadIdx.x * 4;
    const float* __restrict__ col = W + tok;
    float4 v;
    v.x = col[(size_t)(e0 + 0) * VOCAB];
    v.y = col[(size_t)(e0 + 1) * VOCAB];
    v.z = col[(size_t)(e0 + 2) * VOCAB];
    v.w = col[(size_t)(e0 + 3) * VOCAB];
    *reinterpret_cast<float4*>(out + (size_t)pos * EMBED + e0) = v;
}

extern "C" void kernel_launch(void* const* d_in, const int* in_sizes, int n_in,
                              void* d_out, int out_size, void* d_ws, size_t ws_size,
                              hipStream_t stream) {
    const int*   tokens = (const int*)d_in[0];   // (4096,) int32
    const float* W      = (const float*)d_in[1]; // (1024, 50257) fp32
    float*       out    = (float*)d_out;         // (4096, 1024) fp32

    const size_t need = (size_t)(NWPAD * 2 + NTOK * 2) * 4;  // 48 KB
    if (ws_size < need) {
        embed_gather_kernel<<<NTOK, 256, 0, stream>>>(tokens, W, out);
        return;
    }

    unsigned int* mask = (unsigned int*)d_ws;    // 8 KB
    int* wb  = (int*)(mask + NWPAD);             // 8 KB
    int* rep = wb + NWPAD;                       // 16 KB
    int* nxt = rep + NTOK;                       // 16 KB

    setup_kernel<<<1, 1024, 0, stream>>>(tokens, mask, wb, rep, nxt);
    compact_dense_kernel<<<NVSTRIPS * NETILES, 256, 0, stream>>>(W, mask, wb, rep, nxt, out);
}

// Round 6
// 45.251 us; speedup vs baseline: 1.4691x; 1.4691x over previous
//
#include <hip/hip_runtime.h>

// out[pos,e] = W[e, tokens[pos]]  (one_hot @ W.T == embedding gather).
// R6: dense-stream compact, float4 edition. R5's dense read ran at 3.6 TB/s
// because each wave-instruction covered only 256B (4B/lane scalar) across
// 201KB-strided rows -> one DRAM page activation per 256B. Here each thread
// owns 4 consecutive v and loads float4: 1KB contiguous per wave-instruction
// (full page), plain cached loads, strip-fastest block order. Dense 206MB at
// ~6.5 TB/s beats sparse 96MB at 2.2 TB/s (R4 measured).

#define VOCAB 50257
#define EMBED 1024
#define NTOK  4096
#define NWPAD 2048            // padded mask words (>= ceil(50257/32)=1571)
#define VTILE 1024            // vocab span per compact block (4 v per thread)
#define NVSTRIPS 50           // ceil(50257/1024)
#define ETILE 16              // e-rows per compact block; 16*4B = 64B chunk
#define NETILES (EMBED / ETILE)   // 64

__global__ __launch_bounds__(1024) void setup_kernel(
    const int* __restrict__ tokens,
    unsigned int* __restrict__ g_mask,   // [NWPAD]
    int* __restrict__ g_wb,              // [NWPAD]
    int* __restrict__ g_rep,             // [NTOK] head pos per rank
    int* __restrict__ g_nxt) {           // [NTOK] chain
    __shared__ unsigned int mask[NWPAD];
    __shared__ int wb[NWPAD];
    __shared__ int rep[NTOK];
    __shared__ int nxt[NTOK];
    __shared__ int wsum[16];
    const int t = threadIdx.x;

    mask[t] = 0u; mask[t + 1024] = 0u;
    rep[t] = -1; rep[t + 1024] = -1; rep[t + 2048] = -1; rep[t + 3072] = -1;
    __syncthreads();

    const int4 tk = reinterpret_cast<const int4*>(tokens)[t];  // 4 tokens/thread
    atomicOr(&mask[tk.x >> 5], 1u << (tk.x & 31));
    atomicOr(&mask[tk.y >> 5], 1u << (tk.y & 31));
    atomicOr(&mask[tk.z >> 5], 1u << (tk.z & 31));
    atomicOr(&mask[tk.w >> 5], 1u << (tk.w & 31));
    __syncthreads();

    // exclusive scan of per-word popcounts (2 words/thread)
    const unsigned int w0 = mask[2 * t], w1 = mask[2 * t + 1];
    const int c0 = __popc(w0), c1 = __popc(w1);
    const int sum = c0 + c1;
    const int lane = t & 63, wid = t >> 6;
    int inc = sum;
#pragma unroll
    for (int d = 1; d < 64; d <<= 1) {
        const int u = __shfl_up(inc, d, 64);
        if (lane >= d) inc += u;
    }
    if (lane == 63) wsum[wid] = inc;
    __syncthreads();
    if (t == 0) {
        int acc = 0;
#pragma unroll
        for (int i = 0; i < 16; ++i) { const int v = wsum[i]; wsum[i] = acc; acc += v; }
    }
    __syncthreads();
    const int excl = wsum[wid] + inc - sum;
    wb[2 * t] = excl;
    wb[2 * t + 1] = excl + c0;
    __syncthreads();

    // duplicate chains (order race-dependent; output content order-independent)
#pragma unroll
    for (int j = 0; j < 4; ++j) {
        const int pos = t * 4 + j;
        const int tok = (j == 0) ? tk.x : (j == 1) ? tk.y : (j == 2) ? tk.z : tk.w;
        const unsigned int m = mask[tok >> 5];
        const int r = wb[tok >> 5] + __popc(m & ((1u << (tok & 31)) - 1u));
        nxt[pos] = atomicExch(&rep[r], pos);
    }
    __syncthreads();

    g_mask[t] = mask[t]; g_mask[t + 1024] = mask[t + 1024];
    g_wb[t] = wb[t];     g_wb[t + 1024] = wb[t + 1024];
    g_rep[t] = rep[t]; g_rep[t + 1024] = rep[t + 1024];
    g_rep[t + 2048] = rep[t + 2048]; g_rep[t + 3072] = rep[t + 3072];
    g_nxt[t] = nxt[t]; g_nxt[t + 1024] = nxt[t + 1024];
    g_nxt[t + 2048] = nxt[t + 2048]; g_nxt[t + 3072] = nxt[t + 3072];
}

__device__ __forceinline__ float comp(const float4& f, int j) {
    // j is always compile-time constant (called from unrolled loop)
    return (j == 0) ? f.x : (j == 1) ? f.y : (j == 2) ? f.z : f.w;
}

__global__ __launch_bounds__(256) void compact_dense_kernel(
    const float* __restrict__ W,
    const unsigned int* __restrict__ mask,
    const int* __restrict__ wb,
    const int* __restrict__ rep,
    const int* __restrict__ nxt,
    float* __restrict__ out) {
    // strip fastest: consecutive blocks extend the same 16 row-streams
    const int etile = (int)blockIdx.x / NVSTRIPS;
    const int strip = (int)blockIdx.x % NVSTRIPS;
    const int v0 = strip * VTILE + (int)threadIdx.x * 4;  // 4 consecutive v
    const int e0 = etile * ETILE;
    if (v0 >= VOCAB) return;                              // tail strip only

    const unsigned int m = mask[v0 >> 5];
    const unsigned int bits = (m >> (v0 & 31)) & 0xFu;

    // DENSE float4 loads: 64 lanes x 16B = 1KB contiguous per wave-instruction
    // (one full DRAM page per request). Loaded UNCONDITIONALLY to keep the
    // stream gapless; keep-alive asm stops the compiler sinking them into the
    // present-branch (which would re-create R4's sparse 2.2 TB/s pattern).
    float4 val[ETILE];
    const float* __restrict__ src = W + (size_t)e0 * VOCAB + v0;
    if (v0 + 4 <= VOCAB) {
#pragma unroll
        for (int q = 0; q < ETILE; ++q)
            val[q] = *reinterpret_cast<const float4*>(&src[(size_t)q * VOCAB]);
    } else {
        // last partial thread of the tail strip (v0=50256): scalar, guarded
#pragma unroll
        for (int q = 0; q < ETILE; ++q) {
            float a[4] = {0.f, 0.f, 0.f, 0.f};
            for (int j = 0; j < 4; ++j)
                if (v0 + j < VOCAB) a[j] = src[(size_t)q * VOCAB + j];
            val[q] = make_float4(a[0], a[1], a[2], a[3]);
        }
    }
#pragma unroll
    for (int q = 0; q < ETILE; ++q)
        asm volatile("" : "+v"(val[q].x), "+v"(val[q].y), "+v"(val[q].z), "+v"(val[q].w));

    if (!bits) return;
    int r = wb[v0 >> 5] + __popc(m & ((1u << (v0 & 31)) - 1u));

#pragma unroll
    for (int j = 0; j < 4; ++j) {
        if ((bits >> j) & 1u) {
            float4 f[4];
#pragma unroll
            for (int q = 0; q < 4; ++q)
                f[q] = make_float4(comp(val[4 * q + 0], j), comp(val[4 * q + 1], j),
                                   comp(val[4 * q + 2], j), comp(val[4 * q + 3], j));
            int p = rep[r];
            do {
                float4* __restrict__ dst =
                    reinterpret_cast<float4*>(out + (size_t)p * EMBED + e0);
#pragma unroll
                for (int q = 0; q < 4; ++q) dst[q] = f[q];   // 64B contiguous
                p = nxt[p];
            } while (p >= 0);
            ++r;   // next present v in this 4-group has the next rank
        }
    }
}

// Fallback (R1 kernel) if the workspace is too small.
__global__ __launch_bounds__(256) void embed_gather_kernel(
    const int* __restrict__ tokens,
    const float* __restrict__ W,
    float* __restrict__ out) {
    const int pos = blockIdx.x;
    const int tok = tokens[pos];
    const int e0 = (int)threadIdx.x * 4;
    const float* __restrict__ col = W + tok;
    float4 v;
    v.x = col[(size_t)(e0 + 0) * VOCAB];
    v.y = col[(size_t)(e0 + 1) * VOCAB];
    v.z = col[(size_t)(e0 + 2) * VOCAB];
    v.w = col[(size_t)(e0 + 3) * VOCAB];
    *reinterpret_cast<float4*>(out + (size_t)pos * EMBED + e0) = v;
}

extern "C" void kernel_launch(void* const* d_in, const int* in_sizes, int n_in,
                              void* d_out, int out_size, void* d_ws, size_t ws_size,
                              hipStream_t stream) {
    const int*   tokens = (const int*)d_in[0];   // (4096,) int32
    const float* W      = (const float*)d_in[1]; // (1024, 50257) fp32
    float*       out    = (float*)d_out;         // (4096, 1024) fp32

    const size_t need = (size_t)(NWPAD * 2 + NTOK * 2) * 4;  // 48 KB
    if (ws_size < need) {
        embed_gather_kernel<<<NTOK, 256, 0, stream>>>(tokens, W, out);
        return;
    }

    unsigned int* mask = (unsigned int*)d_ws;    // 8 KB
    int* wb  = (int*)(mask + NWPAD);             // 8 KB
    int* rep = wb + NWPAD;                       // 16 KB
    int* nxt = rep + NTOK;                       // 16 KB

    setup_kernel<<<1, 1024, 0, stream>>>(tokens, mask, wb, rep, nxt);
    compact_dense_kernel<<<NETILES * NVSTRIPS, 256, 0, stream>>>(W, mask, wb, rep, nxt, out);
}

// Round 7
// 38.969 us; speedup vs baseline: 1.7059x; 1.1612x over previous
//
#include <hip/hip_runtime.h>

// out[pos,e] = W[e, tokens[pos]]  (one_hot @ W.T == embedding gather).
// R7: single fused kernel. R6's separate 1-block setup kernel cost ~5-7 us of
// pure serialization. Instead each block rebuilds the chains it needs LOCALLY:
// scan all 4096 tokens (16 KB, L2/L3-hot, ~83 hits per 1024-v span) into LDS
// chains, then run R6's proven dense float4 W stream (1KB/wave-instr) with
// 64B chain-walk writes. One dispatch, no global metadata.

#define VOCAB 50257
#define EMBED 1024
#define NTOK  4096
#define THREADS 256
#define VTILE 1024            // vocab span per block (4 v per thread)
#define NVSTRIPS 50           // ceil(50257/1024)
#define ETILE 16              // e-rows per block; 16*4B = 64B write chunk
#define NETILES (EMBED / ETILE)   // 64

__device__ __forceinline__ float fcomp(const float4& f, int j) {
    // j is always a compile-time constant (unrolled callers)
    return (j == 0) ? f.x : (j == 1) ? f.y : (j == 2) ? f.z : f.w;
}
__device__ __forceinline__ int icomp(const int4& f, int j) {
    return (j == 0) ? f.x : (j == 1) ? f.y : (j == 2) ? f.z : f.w;
}

__global__ __launch_bounds__(THREADS) void fused_embed_kernel(
    const int* __restrict__ tokens,
    const float* __restrict__ W,
    float* __restrict__ out) {
    __shared__ int head[VTILE];               // 4 KB: local v -> chain head pos (-1 empty)
    __shared__ unsigned short nxt[NTOK];      // 8 KB: pos -> next pos (0xFFFF = end)

    const int etile = (int)blockIdx.x / NVSTRIPS;
    const int strip = (int)blockIdx.x % NVSTRIPS;
    const int vbase = strip * VTILE;
    const int tid = (int)threadIdx.x;
    const int v0 = vbase + tid * 4;           // 4 consecutive v per thread
    const int e0 = etile * ETILE;

    // ---- phase 1: token scan -> per-block LDS chains (replaces setup kernel).
    // All 256 threads scan 16 tokens each; in-span hits (p=0.02/token) insert.
    int4 tk[4];
#pragma unroll
    for (int j = 0; j < 4; ++j)
        tk[j] = reinterpret_cast<const int4*>(tokens)[tid * 4 + j];
#pragma unroll
    for (int j = 0; j < 4; ++j)
        head[tid * 4 + j] = -1;
    __syncthreads();

#pragma unroll
    for (int j = 0; j < 4; ++j) {
#pragma unroll
        for (int c = 0; c < 4; ++c) {
            const int lv = icomp(tk[j], c) - vbase;
            if ((unsigned)lv < (unsigned)VTILE) {
                const int pos = tid * 16 + j * 4 + c;
                // chain order is race-dependent; output content is not
                const int old = atomicExch(&head[lv], pos);
                nxt[pos] = (unsigned short)old;   // -1 -> 0xFFFF sentinel
            }
        }
    }
    __syncthreads();

    // ---- phase 2: dense W stream + chain-walk writes (R6's proven structure)
    if (v0 >= VOCAB) return;                  // after both barriers: safe

    // DENSE float4 loads: 64 lanes x 16B = 1KB contiguous per wave-instruction
    // (full DRAM page per request). Unconditional; keep-alive asm stops the
    // compiler sinking them into the present-branch (sparse stream = 2.2 TB/s).
    float4 val[ETILE];
    const float* __restrict__ src = W + (size_t)e0 * VOCAB + v0;
    if (v0 + 4 <= VOCAB) {
#pragma unroll
        for (int q = 0; q < ETILE; ++q)
            val[q] = *reinterpret_cast<const float4*>(&src[(size_t)q * VOCAB]);
    } else {
        // last partial thread of the tail strip (v0=50256): scalar, guarded
#pragma unroll
        for (int q = 0; q < ETILE; ++q) {
            float a[4] = {0.f, 0.f, 0.f, 0.f};
            for (int j = 0; j < 4; ++j)
                if (v0 + j < VOCAB) a[j] = src[(size_t)q * VOCAB + j];
            val[q] = make_float4(a[0], a[1], a[2], a[3]);
        }
    }
#pragma unroll
    for (int q = 0; q < ETILE; ++q)
        asm volatile("" : "+v"(val[q].x), "+v"(val[q].y), "+v"(val[q].z), "+v"(val[q].w));

#pragma unroll
    for (int j = 0; j < 4; ++j) {
        int p = head[tid * 4 + j];
        if (p >= 0) {
            float4 f[4];
#pragma unroll
            for (int q = 0; q < 4; ++q)
                f[q] = make_float4(fcomp(val[4 * q + 0], j), fcomp(val[4 * q + 1], j),
                                   fcomp(val[4 * q + 2], j), fcomp(val[4 * q + 3], j));
            do {
                float4* __restrict__ dst =
                    reinterpret_cast<float4*>(out + (size_t)p * EMBED + e0);
#pragma unroll
                for (int q = 0; q < 4; ++q) dst[q] = f[q];   // 64B contiguous chunk
                const unsigned short n = nxt[p];
                p = (n == 0xFFFFu) ? -1 : (int)n;
            } while (p >= 0);
        }
    }
}

extern "C" void kernel_launch(void* const* d_in, const int* in_sizes, int n_in,
                              void* d_out, int out_size, void* d_ws, size_t ws_size,
                              hipStream_t stream) {
    const int*   tokens = (const int*)d_in[0];   // (4096,) int32
    const float* W      = (const float*)d_in[1]; // (1024, 50257) fp32
    float*       out    = (float*)d_out;         // (4096, 1024) fp32

    fused_embed_kernel<<<NETILES * NVSTRIPS, THREADS, 0, stream>>>(tokens, W, out);
}

// Round 8
// 38.526 us; speedup vs baseline: 1.7255x; 1.0115x over previous
//
#include <hip/hip_runtime.h>

// out[pos,e] = W[e, tokens[pos]]  (one_hot @ W.T == embedding gather).
// R8: R7 + ISSUE-EARLY W loads (T14 split). R7 issued the 16 dense float4 W
// loads only after token-scan + 2 barriers + LDS atomics (~400-800 dead cycles
// per block start). Here the W loads are issued FIRST; the token wait is a
// counted vmcnt that leaves them in flight, and the forced wait (keep-alive
// asm) sits after the barriers. Everything else identical to R7 (proven:
// dense 1KB/wave-instr stream @ ~5.7 TB/s, 64B chain-walk writes).

#define VOCAB 50257
#define EMBED 1024
#define NTOK  4096
#define THREADS 256
#define VTILE 1024            // vocab span per block (4 v per thread)
#define NVSTRIPS 50           // ceil(50257/1024)
#define ETILE 16              // e-rows per block; 16*4B = 64B write chunk
#define NETILES (EMBED / ETILE)   // 64

__device__ __forceinline__ float fcomp(const float4& f, int j) {
    // j is always a compile-time constant (unrolled callers)
    return (j == 0) ? f.x : (j == 1) ? f.y : (j == 2) ? f.z : f.w;
}
__device__ __forceinline__ int icomp(const int4& f, int j) {
    return (j == 0) ? f.x : (j == 1) ? f.y : (j == 2) ? f.z : f.w;
}

__global__ __launch_bounds__(THREADS) void fused_embed_kernel(
    const int* __restrict__ tokens,
    const float* __restrict__ W,
    float* __restrict__ out) {
    __shared__ int head[VTILE];               // 4 KB: local v -> chain head pos (-1 empty)
    __shared__ unsigned short nxt[NTOK];      // 8 KB: pos -> next pos (0xFFFF = end)

    const int etile = (int)blockIdx.x / NVSTRIPS;
    const int strip = (int)blockIdx.x % NVSTRIPS;
    const int vbase = strip * VTILE;
    const int tid = (int)threadIdx.x;
    const int v0 = vbase + tid * 4;           // 4 consecutive v per thread
    const int e0 = etile * ETILE;
    const bool full = (v0 + 4 <= VOCAB);

    // LDS head init (independent of any load)
#pragma unroll
    for (int j = 0; j < 4; ++j)
        head[tid * 4 + j] = -1;

    // Token loads issued first: the atomics' wait is then a COUNTED vmcnt
    // that leaves the W loads (issued below) in flight.
    int4 tk[4];
#pragma unroll
    for (int j = 0; j < 4; ++j)
        tk[j] = reinterpret_cast<const int4*>(tokens)[tid * 4 + j];

    // ISSUE-EARLY dense W stream: 64 lanes x 16B = 1KB contiguous per
    // wave-instruction (full DRAM page). In flight across all of phase 1.
    float4 val[ETILE];
    const float* __restrict__ src = W + (size_t)e0 * VOCAB + v0;
    if (full) {
#pragma unroll
        for (int q = 0; q < ETILE; ++q)
            val[q] = *reinterpret_cast<const float4*>(&src[(size_t)q * VOCAB]);
    }

    __syncthreads();

    // phase 1: token scan -> per-block LDS chains (~83 hits per 1024-v span).
#pragma unroll
    for (int j = 0; j < 4; ++j) {
#pragma unroll
        for (int c = 0; c < 4; ++c) {
            const int lv = icomp(tk[j], c) - vbase;
            if ((unsigned)lv < (unsigned)VTILE) {
                const int pos = tid * 16 + j * 4 + c;
                // chain order is race-dependent; output content is not
                const int old = atomicExch(&head[lv], pos);
                nxt[pos] = (unsigned short)old;   // -1 -> 0xFFFF sentinel
            }
        }
    }
    __syncthreads();

    if (v0 >= VOCAB) return;                  // after both barriers: safe

    if (!full) {
        // last partial thread of the tail strip (v0=50256): scalar, guarded.
        // 16 threads total across the grid — divergence negligible.
#pragma unroll
        for (int q = 0; q < ETILE; ++q) {
            float a[4] = {0.f, 0.f, 0.f, 0.f};
            for (int j = 0; j < 4; ++j)
                if (v0 + j < VOCAB) a[j] = src[(size_t)q * VOCAB + j];
            val[q] = make_float4(a[0], a[1], a[2], a[3]);
        }
    }

    // Keep-alive: forces the vmcnt wait HERE (after phase 1), and stops the
    // compiler sinking the dense loads into the present-branch (which would
    // re-create the 2.2 TB/s sparse stream).
#pragma unroll
    for (int q = 0; q < ETILE; ++q)
        asm volatile("" : "+v"(val[q].x), "+v"(val[q].y), "+v"(val[q].z), "+v"(val[q].w));

#pragma unroll
    for (int j = 0; j < 4; ++j) {
        int p = head[tid * 4 + j];
        if (p >= 0) {
            float4 f[4];
#pragma unroll
            for (int q = 0; q < 4; ++q)
                f[q] = make_float4(fcomp(val[4 * q + 0], j), fcomp(val[4 * q + 1], j),
                                   fcomp(val[4 * q + 2], j), fcomp(val[4 * q + 3], j));
            do {
                float4* __restrict__ dst =
                    reinterpret_cast<float4*>(out + (size_t)p * EMBED + e0);
#pragma unroll
                for (int q = 0; q < 4; ++q) dst[q] = f[q];   // 64B contiguous chunk
                const unsigned short n = nxt[p];
                p = (n == 0xFFFFu) ? -1 : (int)n;
            } while (p >= 0);
        }
    }
}

extern "C" void kernel_launch(void* const* d_in, const int* in_sizes, int n_in,
                              void* d_out, int out_size, void* d_ws, size_t ws_size,
                              hipStream_t stream) {
    const int*   tokens = (const int*)d_in[0];   // (4096,) int32
    const float* W      = (const float*)d_in[1]; // (1024, 50257) fp32
    float*       out    = (float*)d_out;         // (4096, 1024) fp32

    fused_embed_kernel<<<NETILES * NVSTRIPS, THREADS, 0, stream>>>(tokens, W, out);
}